// Round 9
// baseline (329.887 us; speedup 1.0000x reference)
//
#include <hip/hip_runtime.h>

// RGCN vulnerability classifier, fp32 in/out, MI355X.
// r19b = r19 resubmitted (r8 bench was an infra failure: "container failed twice";
// kernel audit found no fault/hang risk). gather1 restructured per r18 rocprof
// (58.3us, 1.3TB/s, VALU 38%, latency-bound): block owns 64 consecutive nodes
// (their CSR slots are contiguous); Phase A = edge-parallel 16-lane groups (16
// independent slot streams per block, uniform trip, coalesced edata) into LDS
// h[64][33] via float atomicAdd (stride-33 conflict-free); Phase B = relu+bias
// pass then 16-node x 16-col matvec with Vt in registers (no shfl, no idle
// lanes). Everything else identical to r18 (258.7us).

#define N_NODES 100000
#define N_REL   8
#define N_EDGES 80000
#define IN_F    128
#define HID     32
#define N_GRAPHS 64
#define NCAT    (N_REL * HID)       // 256
#define N_KEYS  (N_NODES * N_REL)   // 800000
#define TOT_E   (N_REL * N_EDGES)   // 640000
#define DEG_BLOCKS  (TOT_E / 256)   // 2500
#define GEMM_BLOCKS ((N_NODES / 16 + 3) / 4)   // 1563
#define GID_BLOCKS  ((N_NODES + 1023) / 1024)  // 98
#define G1_NB 64                    // nodes per gather1 block

constexpr int TILE = 256;   // tier-3 projection block
constexpr int KC   = 32;

typedef __attribute__((ext_vector_type(8))) short bf16x8;
typedef __attribute__((ext_vector_type(4))) float f32x4;

__device__ __forceinline__ ushort f2bf(float v) {
  unsigned u = __builtin_bit_cast(unsigned, v);
  u = (u + 0x7fffu + ((u >> 16) & 1u)) >> 16;   // RNE
  return (ushort)u;
}
__device__ __forceinline__ float bf2f(ushort h) {
  unsigned u = ((unsigned)h) << 16;
  return __builtin_bit_cast(float, u);
}

__global__ __launch_bounds__(256) void rsqrt_kernel(float* __restrict__ p, int count) {
  int i = blockIdx.x * 256 + threadIdx.x;
  if (i < count) {
    int d = ((const int*)p)[i];
    p[i] = rsqrtf((float)(d < 1 ? 1 : d));
  }
}

// Wt1[n][k] = bf16(W1[r][k][j]), n=r*32+j (B^T for MFMA).
// Vt[n][k] = bf16( sum_j W2[r][k][j]*Wc[j][c] ), n=r*2+c (W2@Wc fold).
__global__ __launch_bounds__(256) void prep_w_kernel(const float* __restrict__ W1, const float* __restrict__ W2,
                                                     const float* __restrict__ Wc,
                                                     ushort* __restrict__ Wt1, ushort* __restrict__ Vt) {
  int i = blockIdx.x * 256 + threadIdx.x;
  if (i < NCAT * IN_F) {
    int n = i >> 7, k = i & 127;
    int r = n >> 5, j = n & 31;
    Wt1[i] = f2bf(W1[r * (IN_F * HID) + k * HID + j]);
  } else {
    int q = i - NCAT * IN_F;
    if (q < 16 * HID) {
      int n = q >> 5, k = q & 31;
      int r = n >> 1, c = n & 1;
      float s = 0.f;
#pragma unroll
      for (int j = 0; j < HID; j++) s += W2[r * (HID * HID) + k * HID + j] * Wc[j * 2 + c];
      Vt[q] = f2bf(s);
    }
  }
}

// FUSED: deg/cnt histogram (atomic-RMW-bound, ~0 CU use) + gemm1 (MFMA-bound)
// + gid node-count histogram (98 tail blocks, rides in the atomic slack).
__global__ __launch_bounds__(256, 4) void fused_deg_gemm1(const int* __restrict__ src, const int* __restrict__ dst,
                                                          int* __restrict__ dego, int* __restrict__ cnt,
                                                          int* __restrict__ epos,
                                                          const float* __restrict__ A, const ushort* __restrict__ Bt,
                                                          ushort* __restrict__ Y, int M,
                                                          const int* __restrict__ gid, float* __restrict__ gcnt) {
  __shared__ ushort smem[17408];   // gemm path; reused as int hist by gid path
  int bid = blockIdx.x;
  int role, rid;   // 0=gemm 1=deg 2=gid
  if (bid < 2 * GEMM_BLOCKS) { role = bid & 1; rid = bid >> 1; }
  else if (bid < GEMM_BLOCKS + DEG_BLOCKS) { role = 1; rid = GEMM_BLOCKS + (bid - 2 * GEMM_BLOCKS); }
  else { role = 2; rid = bid - (GEMM_BLOCKS + DEG_BLOCKS); }

  if (role == 1) {
    // ---- deg role: one edge per thread ----
    int i = rid * 256 + (int)threadIdx.x;
    int s = src[i], d = dst[i];
    int r = i / N_EDGES;
    atomicAdd(&dego[r * N_NODES + s], 1);
    epos[i] = atomicAdd(&cnt[d * N_REL + r], 1);
    return;
  }
  if (role == 2) {
    // ---- gid node-count histogram ----
    int* gh = (int*)smem;
    int t = threadIdx.x;
    if (t < N_GRAPHS) gh[t] = 0;
    __syncthreads();
    int base = rid * 1024;
#pragma unroll
    for (int k = 0; k < 4; k++) {
      int n = base + k * 256 + t;
      if (n < N_NODES) atomicAdd(&gh[gid[n]], 1);
    }
    __syncthreads();
    if (t < N_GRAPHS) atomicAdd(&gcnt[t], (float)gh[t]);
    return;
  }

  // ---- gemm role ----
  int wave = __builtin_amdgcn_readfirstlane(threadIdx.x >> 6);
  int lane = threadIdx.x & 63;
  int t = threadIdx.x;
  int m0 = (rid * 4 + wave) * 16;
  int me = (m0 <= M - 16) ? m0 : (M - 16);   // clamped row base for all loads
  int row = lane & 15, quad = lane >> 4;

  bf16x8 af[4];
#pragma unroll
  for (int kq = 0; kq < 4; kq++) {
    const float* ap = &A[(size_t)(me + row) * IN_F + kq * 32 + quad * 8];
    float4 a0 = *(const float4*)ap;
    float4 a1 = *(const float4*)(ap + 4);
    bf16x8 a;
    a[0] = (short)f2bf(a0.x); a[1] = (short)f2bf(a0.y); a[2] = (short)f2bf(a0.z); a[3] = (short)f2bf(a0.w);
    a[4] = (short)f2bf(a1.x); a[5] = (short)f2bf(a1.y); a[6] = (short)f2bf(a1.z); a[7] = (short)f2bf(a1.w);
    af[kq] = a;
  }

  f32x4 acc[16];
#pragma unroll
  for (int nt = 0; nt < 16; nt++) acc[nt] = (f32x4){0.f, 0.f, 0.f, 0.f};

  for (int p = 0; p < 2; p++) {
    __syncthreads();
    const ushort* bsrc = Bt + (size_t)p * (128 * IN_F);
#pragma unroll
    for (int i = 0; i < 8; i++) {
      int c = t + i * 256;
      int rr2 = c >> 4, cc = c & 15;
      uint4 v = *(const uint4*)&bsrc[rr2 * IN_F + cc * 8];
      *(uint4*)&smem[rr2 * 136 + cc * 8] = v;
    }
    __syncthreads();
#pragma unroll
    for (int kq = 0; kq < 4; kq++) {
#pragma unroll
      for (int nt2 = 0; nt2 < 8; nt2++) {
        bf16x8 b = *(const bf16x8*)&smem[(nt2 * 16 + row) * 136 + kq * 32 + quad * 8];
        acc[p * 8 + nt2] = __builtin_amdgcn_mfma_f32_16x16x32_bf16(af[kq], b, acc[p * 8 + nt2], 0, 0, 0);
      }
    }
  }
  __syncthreads();

  ushort* myt = &smem[wave * 4160];
#pragma unroll
  for (int nt = 0; nt < 16; nt++) {
#pragma unroll
    for (int i = 0; i < 4; i++)
      myt[(quad * 4 + i) * 260 + nt * 16 + row] = f2bf(acc[nt][i]);
  }
  if (m0 <= M - 16) {
    ushort* ybase = &Y[(size_t)m0 * NCAT];
#pragma unroll
    for (int k = 0; k < 8; k++) {
      int g = k * 512 + lane * 8;
      int r2 = g >> 8, c2 = g & 255;
      const ushort* sp = &myt[r2 * 260 + c2];
      uint4 v;
      v.x = *(const uint*)(sp + 0);
      v.y = *(const uint*)(sp + 2);
      v.z = *(const uint*)(sp + 4);
      v.w = *(const uint*)(sp + 6);
      *(uint4*)&ybase[g] = v;
    }
  }
}

// ---- exclusive scan over cnt[N_KEYS] -> rp (block-local; part adds by consumers) ----
__global__ __launch_bounds__(256) void scan1_kernel(const int* __restrict__ in, int* __restrict__ out,
                                                    int* __restrict__ partial, int n) {
  __shared__ int ts[256];
  int b0 = blockIdx.x * 1024;
  int t = threadIdx.x;
  int v[4]; int s = 0;
#pragma unroll
  for (int k = 0; k < 4; k++) {
    int idx = b0 + t * 4 + k;
    v[k] = s;
    s += (idx < n) ? in[idx] : 0;
  }
  ts[t] = s;
  __syncthreads();
  for (int off = 1; off < 256; off <<= 1) {
    int xv = (t >= off) ? ts[t - off] : 0;
    __syncthreads();
    ts[t] += xv;
    __syncthreads();
  }
  int texcl = (t == 0) ? 0 : ts[t - 1];
#pragma unroll
  for (int k = 0; k < 4; k++) {
    int idx = b0 + t * 4 + k;
    if (idx < n) out[idx] = texcl + v[k];
  }
  if (t == 255) {
    partial[blockIdx.x] = ts[255];
    if (b0 + 1024 >= n) out[n] = ts[255];   // unique last covering block
  }
}

__global__ __launch_bounds__(256) void scan2_kernel(int* __restrict__ partial, int nb) {
  __shared__ int ts[256];
  int t = threadIdx.x;
  int v[4]; int s = 0;
#pragma unroll
  for (int k = 0; k < 4; k++) {
    int idx = t * 4 + k;
    v[k] = s;
    s += (idx < nb) ? partial[idx] : 0;
  }
  ts[t] = s;
  __syncthreads();
  for (int off = 1; off < 256; off <<= 1) {
    int xv = (t >= off) ? ts[t - off] : 0;
    __syncthreads();
    ts[t] += xv;
    __syncthreads();
  }
  int texcl = (t == 0) ? 0 : ts[t - 1];
#pragma unroll
  for (int k = 0; k < 4; k++) {
    int idx = t * 4 + k;
    if (idx < nb) partial[idx] = texcl + v[k];
  }
}

// CSR fill, atomic-free: slot = rp(key)+epos[i]. 16B record {ecol1, w, d, 0}.
__global__ __launch_bounds__(256) void fill_kernel(const int* __restrict__ src, const int* __restrict__ dst,
                                                   const int* __restrict__ rp, const int* __restrict__ part,
                                                   const int* __restrict__ epos, const int* __restrict__ dego,
                                                   int4* __restrict__ edata) {
  int i = blockIdx.x * 256 + threadIdx.x;
  int d = dst[i];
  int s = src[i];
  int r = i / N_EDGES;
  int key = d * N_REL + r;
  int b = rp[key] + part[key >> 10];
  int k1 = key + 1;
  int e2 = rp[k1] + part[k1 >> 10];
  int c = e2 - b;
  int t = b + epos[i];
  int dg = dego[r * N_NODES + s];
  float w = rsqrtf((float)(dg < 1 ? 1 : dg)) * rsqrtf((float)(c < 1 ? 1 : c));
  int4 e;
  e.x = s * NCAT + r * HID;            // ushort index into Ys (ecol2 = e.x>>4)
  e.y = __builtin_bit_cast(int, w);
  e.z = d;
  e.w = 0;
  edata[t] = e;
}

// Gather layer1 + layer-2 projection, node-block edge-parallel:
// block owns nodes [d0, d0+64); their CSR slots are contiguous. Phase A:
// 16-lane groups stream slots (16 independent streams/block), LDS atomicAdd
// into h[64][33] (stride-33 conflict-free per group). Phase B: relu+bias
// pass, then 16 nodes x 16 cols matvec, Vt in registers.
__global__ __launch_bounds__(256) void gather1_kernel(const ushort* __restrict__ Ys, const int4* __restrict__ edata,
                                                      const int* __restrict__ rp, const int* __restrict__ part,
                                                      const float* __restrict__ b1, const ushort* __restrict__ Vt,
                                                      float* __restrict__ Ys2) {
  __shared__ float h[G1_NB][33];
  __shared__ float sbias[HID];
  int t = threadIdx.x;
  int d0 = blockIdx.x * G1_NB;
  int d1 = d0 + G1_NB; if (d1 > N_NODES) d1 = N_NODES;
  for (int i = t; i < G1_NB * 33; i += 256) (&h[0][0])[i] = 0.f;
  if (t < HID) {
    float sb = 0.f;
#pragma unroll
    for (int q = 0; q < N_REL; q++) sb += b1[q * HID + t];
    sbias[t] = sb;
  }
  __syncthreads();

  int k0 = d0 * N_REL, k1e = d1 * N_REL;
  int base = rp[k0] + part[k0 >> 10];
  int endp = rp[k1e] + part[k1e >> 10];

  int g = t >> 4;            // 16 slot streams
  int j2 = (t & 15) * 2;     // feature pair
  for (int s = base + g; s < endp; s += 16) {
    int4 e = edata[s];       // 16 lanes same addr -> broadcast
    float w = __builtin_bit_cast(float, e.y);
    uint yy = *(const uint*)&Ys[(size_t)e.x + j2];   // 4B of the 64B row read
    float y0 = bf2f((ushort)(yy & 0xffffu));
    float y1 = bf2f((ushort)(yy >> 16));
    int dl = e.z - d0;
    atomicAdd(&h[dl][j2], w * y0);
    atomicAdd(&h[dl][j2 + 1], w * y1);
  }
  __syncthreads();

  // relu + bias in place
  for (int i = t; i < G1_NB * HID; i += 256) {
    int ln = i >> 5, k = i & 31;
    h[ln][k] = fmaxf(h[ln][k] + sbias[k], 0.f);
  }
  __syncthreads();

  // matvec: 16 nodes x 16 cols per round
  int ln = t >> 4, c = t & 15;
  float vreg[HID];
#pragma unroll
  for (int q = 0; q < 4; q++) {
    bf16x8 v = *(const bf16x8*)&Vt[c * HID + q * 8];
#pragma unroll
    for (int m = 0; m < 8; m++) vreg[q * 8 + m] = bf2f((ushort)v[m]);
  }
#pragma unroll
  for (int nb = 0; nb < G1_NB; nb += 16) {
    int d = d0 + nb + ln;
    if (d < d1) {
      float acc = 0.f;
#pragma unroll
      for (int k = 0; k < HID; k++) acc += h[nb + ln][k] * vreg[k];
      Ys2[(size_t)d * 16 + c] = acc;
    }
  }
}

// Gather layer2 + pooling, STREAMING: grid-stride over slots; gid[e.z] is
// d-ordered (quasi-sequential); only Ys2 read is random. Counts via gid hist.
__global__ __launch_bounds__(256) void gather2_pool_kernel(const float* __restrict__ Ys2,
                                                           const int4* __restrict__ edata,
                                                           const int* __restrict__ gid,
                                                           float* __restrict__ gpool) {
  __shared__ float lp[N_GRAPHS * 2];
  int t = threadIdx.x;
  if (t < N_GRAPHS * 2) lp[t] = 0.f;
  __syncthreads();
  for (int sidx = blockIdx.x * 256 + t; sidx < TOT_E; sidx += gridDim.x * 256) {
    int4 e = edata[sidx];
    float w = __builtin_bit_cast(float, e.y);
    float2 y = *(const float2*)&Ys2[e.x >> 4];
    int g = gid[e.z];
    atomicAdd(&lp[g * 2 + 0], w * y.x);
    atomicAdd(&lp[g * 2 + 1], w * y.y);
  }
  __syncthreads();
  if (t < N_GRAPHS * 2) atomicAdd(&gpool[t], lp[t]);
}

// out[g] = gpool[g]/cnt + (sum_r b2[r]) @ Wc + bc   (cnt==0 -> bc exactly)
__global__ void final_kernel(const float* __restrict__ gpool, const float* __restrict__ gcnt,
                             const float* __restrict__ b2, const float* __restrict__ Wc,
                             const float* __restrict__ bc, float* __restrict__ out) {
  int g = threadIdx.x;
  if (g >= N_GRAPHS) return;
  float c0 = 0.f, c1 = 0.f;
#pragma unroll
  for (int k = 0; k < HID; k++) {
    float sb = 0.f;
#pragma unroll
    for (int r = 0; r < N_REL; r++) sb += b2[r * HID + k];
    c0 += sb * Wc[k * 2 + 0];
    c1 += sb * Wc[k * 2 + 1];
  }
  float cntv = gcnt[g];
  if (cntv > 0.f) {
    out[g * 2 + 0] = gpool[g * 2 + 0] / cntv + c0 + bc[0];
    out[g * 2 + 1] = gpool[g * 2 + 1] / cntv + c1 + bc[1];
  } else {
    out[g * 2 + 0] = bc[0];
    out[g * 2 + 1] = bc[1];
  }
}

// ---- Tier-3 fp32 fallback kernels (small ws) ----
__global__ __launch_bounds__(256) void deg_kernel(const int* __restrict__ src, const int* __restrict__ dst,
                                                  int* __restrict__ dego, int* __restrict__ degi, int n_rel) {
  int i = blockIdx.x * 256 + threadIdx.x;
  if (i < n_rel * N_EDGES) {
    int r = i / N_EDGES;
    atomicAdd(&dego[r * N_NODES + src[i]], 1);
    atomicAdd(&degi[r * N_NODES + dst[i]], 1);
  }
}

__global__ __launch_bounds__(256) void proj1_kernel(const float* __restrict__ x, const float* __restrict__ W1r0,
                                                    const float* __restrict__ rs_o, float* __restrict__ hw,
                                                    int n0, int n1, int hw_nodes) {
  int rr = blockIdx.y;
  int nb = n0 + blockIdx.x * TILE;
  int t = threadIdx.x;
  __shared__ float xs[TILE][KC + 4];
  const float* __restrict__ Wr = W1r0 + (size_t)rr * (IN_F * HID);
  float acc[HID];
#pragma unroll
  for (int j = 0; j < HID; j++) acc[j] = 0.f;
  for (int kc = 0; kc < IN_F; kc += KC) {
    __syncthreads();
#pragma unroll
    for (int i = 0; i < (TILE * KC / 4) / 256; i++) {
      int q = t + i * 256;
      int nn = q >> 3, k4 = q & 7;
      int n = nb + nn;
      float4 v = make_float4(0.f, 0.f, 0.f, 0.f);
      if (n < n1) v = *(const float4*)&x[(size_t)n * IN_F + kc + k4 * 4];
      *(float4*)&xs[nn][k4 * 4] = v;
    }
    __syncthreads();
#pragma unroll
    for (int k4 = 0; k4 < KC / 4; k4++) {
      float4 xv = *(const float4*)&xs[t][k4 * 4];
      const float* wk = &Wr[(kc + k4 * 4) * HID];
#pragma unroll
      for (int j = 0; j < HID; j++) acc[j] += xv.x * wk[j];
#pragma unroll
      for (int j = 0; j < HID; j++) acc[j] += xv.y * wk[HID + j];
#pragma unroll
      for (int j = 0; j < HID; j++) acc[j] += xv.z * wk[2 * HID + j];
#pragma unroll
      for (int j = 0; j < HID; j++) acc[j] += xv.w * wk[3 * HID + j];
    }
  }
  int n = nb + t;
  if (n < n1) {
    float s = rs_o[(size_t)rr * N_NODES + n];
    float* o = &hw[((size_t)rr * hw_nodes + (n - n0)) * HID];
#pragma unroll
    for (int j4 = 0; j4 < HID / 4; j4++) {
      float4 v = make_float4(acc[j4 * 4] * s, acc[j4 * 4 + 1] * s, acc[j4 * 4 + 2] * s, acc[j4 * 4 + 3] * s);
      *(float4*)&o[j4 * 4] = v;
    }
  }
}

__global__ __launch_bounds__(256) void proj2_kernel(const float* __restrict__ acc1, const float* __restrict__ b1,
                                                    const float* __restrict__ W2r0, const float* __restrict__ rs_o,
                                                    float* __restrict__ hw, int n0, int n1, int hw_nodes) {
  int n = n0 + blockIdx.x * 256 + threadIdx.x;
  if (n >= n1) return;
  int rr = blockIdx.y;
  float h1[HID];
#pragma unroll
  for (int j4 = 0; j4 < HID / 4; j4++) {
    float4 v = *(const float4*)&acc1[(size_t)n * HID + j4 * 4];
    h1[j4 * 4 + 0] = v.x; h1[j4 * 4 + 1] = v.y; h1[j4 * 4 + 2] = v.z; h1[j4 * 4 + 3] = v.w;
  }
#pragma unroll
  for (int j = 0; j < HID; j++) {
    float sb = 0.f;
#pragma unroll
    for (int q = 0; q < N_REL; q++) sb += b1[q * HID + j];
    h1[j] = fmaxf(h1[j] + sb, 0.f);
  }
  const float* __restrict__ Wr = W2r0 + (size_t)rr * (HID * HID);
  float acc[HID];
#pragma unroll
  for (int j = 0; j < HID; j++) acc[j] = 0.f;
#pragma unroll
  for (int k = 0; k < HID; k++) {
    float hv = h1[k];
#pragma unroll
    for (int j = 0; j < HID; j++) acc[j] += hv * Wr[k * HID + j];
  }
  float s = rs_o[(size_t)rr * N_NODES + n];
  float* o = &hw[((size_t)rr * hw_nodes + (n - n0)) * HID];
#pragma unroll
  for (int j4 = 0; j4 < HID / 4; j4++) {
    float4 v = make_float4(acc[j4 * 4] * s, acc[j4 * 4 + 1] * s, acc[j4 * 4 + 2] * s, acc[j4 * 4 + 3] * s);
    *(float4*)&o[j4 * 4] = v;
  }
}

__global__ __launch_bounds__(256) void scatter_kernel(const float* __restrict__ hw, const int* __restrict__ src,
                                                      const int* __restrict__ dst, const float* __restrict__ rs_i,
                                                      float* __restrict__ acc, int nr, int n0, int n1, int hw_nodes) {
  long i = (long)blockIdx.x * 256 + threadIdx.x;
  long total = (long)nr * N_EDGES * HID;
  if (i >= total) return;
  int j = (int)(i & (HID - 1));
  long e = i >> 5;
  int rr = (int)(e / N_EDGES);
  int ee = (int)(e - (long)rr * N_EDGES);
  int s = src[rr * N_EDGES + ee];
  if (s < n0 || s >= n1) return;
  int d = dst[rr * N_EDGES + ee];
  float v = hw[((size_t)rr * hw_nodes + (s - n0)) * HID + j] * rs_i[(size_t)rr * N_NODES + d];
  atomicAdd(&acc[(size_t)d * HID + j], v);
}

__global__ __launch_bounds__(256) void pool_kernel(const float* __restrict__ acc2, const float* __restrict__ b2,
                                                   const int* __restrict__ gid, float* __restrict__ gpool,
                                                   float* __restrict__ gcnt) {
  __shared__ float lp[N_GRAPHS * HID];
  __shared__ float lc[N_GRAPHS];
  int t = threadIdx.x;
  for (int i = t; i < N_GRAPHS * HID; i += 256) lp[i] = 0.f;
  if (t < N_GRAPHS) lc[t] = 0.f;
  __syncthreads();
  int j = t & (HID - 1);
  int grp = t >> 5;
  float sb = 0.f;
#pragma unroll
  for (int q = 0; q < N_REL; q++) sb += b2[q * HID + j];
  for (int n = blockIdx.x * 8 + grp; n < N_NODES; n += gridDim.x * 8) {
    int g = gid[n];
    float v = acc2[(size_t)n * HID + j] + sb;
    atomicAdd(&lp[g * HID + j], v);
    if (j == 0) atomicAdd(&lc[g], 1.f);
  }
  __syncthreads();
  for (int i = t; i < N_GRAPHS * HID; i += 256) atomicAdd(&gpool[i], lp[i]);
  if (t < N_GRAPHS) atomicAdd(&gcnt[t], lc[t]);
}

__global__ void final3_kernel(const float* __restrict__ gpool, const float* __restrict__ gcnt,
                              const float* __restrict__ Wc, const float* __restrict__ bc,
                              float* __restrict__ out) {
  int g = threadIdx.x;
  if (g >= N_GRAPHS) return;
  float inv = 1.f / fmaxf(gcnt[g], 1.f);
  float o0 = bc[0], o1 = bc[1];
#pragma unroll
  for (int k = 0; k < HID; k++) {
    float p = gpool[g * HID + k] * inv;
    o0 += p * Wc[k * 2 + 0];
    o1 += p * Wc[k * 2 + 1];
  }
  out[g * 2 + 0] = o0;
  out[g * 2 + 1] = o1;
}

extern "C" void kernel_launch(void* const* d_in, const int* in_sizes, int n_in,
                              void* d_out, int out_size, void* d_ws, size_t ws_size,
                              hipStream_t stream) {
  const float* x  = (const float*)d_in[0];
  const int* src  = (const int*)d_in[1];
  const int* dst  = (const int*)d_in[2];
  const int* gid  = (const int*)d_in[3];
  const float* W1 = (const float*)d_in[5];
  const float* b1 = (const float*)d_in[6];
  const float* W2 = (const float*)d_in[7];
  const float* b2 = (const float*)d_in[8];
  const float* Wc = (const float*)d_in[9];
  const float* bc = (const float*)d_in[10];
  float* out = (float*)d_out;

  float* ws = (float*)d_ws;
  const size_t NF = (size_t)N_NODES * HID;           // 3.2M
  const size_t RN = (size_t)N_REL * N_NODES;         // 800k
  const size_t POOLF = N_GRAPHS * HID + N_GRAPHS;
  size_t wsf = ws_size / 4;

  const size_t T1_NEED = 22500000;   // ~90 MB (actual ~21.6M float slots)

  if (wsf >= T1_NEED) {
    // ---- Tier 1 layout ----
    float* gpool = ws;                               // 128  (zero region start)
    float* gcnt  = gpool + N_GRAPHS * 2;             // 64
    int*   dego  = (int*)(gcnt + N_GRAPHS);          // RN raw out-degree counts
    int*   cnt   = dego + RN;                        // N_KEYS (raw in-degree counts; zero region end)
    int*   epos  = cnt + N_KEYS;                     // TOT_E (within-bucket ranks)
    int*   rp    = epos + TOT_E;                     // N_KEYS + 8 (block-local scan)
    int*   part  = rp + N_KEYS + 8;                  // 1024
    int4*  edata = (int4*)(part + 1024);             // TOT_E x 16B packed edge records
    float* Ys2   = (float*)(edata + TOT_E);          // N*16
    ushort* Ys   = (ushort*)(Ys2 + (size_t)N_NODES * 16);   // N*256 ushorts
    ushort* Wt1  = Ys + (size_t)N_NODES * NCAT;             // 256*128 ushorts
    ushort* Vt   = Wt1 + NCAT * IN_F;                       // 16*32 ushorts

    size_t zbytes = (N_GRAPHS * 3 + RN + (size_t)N_KEYS) * 4;   // ~6.4 MB
    hipMemsetAsync(ws, 0, zbytes, stream);

    prep_w_kernel<<<(NCAT * IN_F + 16 * HID + 255) / 256, 256, 0, stream>>>(W1, W2, Wc, Wt1, Vt);
    fused_deg_gemm1<<<DEG_BLOCKS + GEMM_BLOCKS + GID_BLOCKS, 256, 0, stream>>>(src, dst, dego, cnt, epos,
                                                                               x, Wt1, Ys, N_NODES, gid, gcnt);

    int sblocks = (N_KEYS + 1023) / 1024;
    scan1_kernel<<<sblocks, 256, 0, stream>>>(cnt, rp, part, N_KEYS);
    scan2_kernel<<<1, 256, 0, stream>>>(part, sblocks);
    fill_kernel<<<TOT_E / 256, 256, 0, stream>>>(src, dst, rp, part, epos, dego, edata);

    int g1blocks = (N_NODES + G1_NB - 1) / G1_NB;
    gather1_kernel<<<g1blocks, 256, 0, stream>>>(Ys, edata, rp, part, b1, Vt, Ys2);
    gather2_pool_kernel<<<416, 256, 0, stream>>>(Ys2, edata, gid, gpool);
    final_kernel<<<1, 64, 0, stream>>>(gpool, gcnt, b2, Wc, bc, out);
  } else {
    // ---- Tier 3: fp32 per-relation fallback, node-chunked hw ----
    float* acc1  = ws;
    float* acc2  = acc1 + NF;
    float* gpool = acc2 + NF;
    float* gcnt  = gpool + N_GRAPHS * HID;
    float* rsb   = ws + (2 * NF + POOLF);
    size_t zf = 2 * NF + POOLF;
    float* rs_o = rsb;
    float* rs_i = rsb + N_NODES;
    float* hw = rsb + 2 * N_NODES;
    size_t fixed3 = zf + 2 * N_NODES;
    size_t avail = (wsf > fixed3) ? (wsf - fixed3) : 0;
    long chunk = (long)(avail / HID) & ~255L;
    if (chunk < 256) chunk = 256;
    if (chunk > N_NODES) chunk = N_NODES;

    size_t zb = zf * 4; if (zb > ws_size) zb = ws_size;
    hipMemsetAsync(d_ws, 0, zb, stream);

    for (int layer = 0; layer < 2; layer++) {
      for (int r = 0; r < N_REL; r++) {
        hipMemsetAsync(rs_o, 0, 2 * N_NODES * 4, stream);
        deg_kernel<<<(N_EDGES + 255) / 256, 256, 0, stream>>>(src + (size_t)r * N_EDGES, dst + (size_t)r * N_EDGES,
                                                              (int*)rs_o, (int*)rs_i, 1);
        rsqrt_kernel<<<(2 * N_NODES + 255) / 256, 256, 0, stream>>>(rs_o, 2 * N_NODES);
        for (long n0 = 0; n0 < N_NODES; n0 += chunk) {
          long n1 = n0 + chunk; if (n1 > N_NODES) n1 = N_NODES;
          int tiles = (int)((n1 - n0 + TILE - 1) / TILE);
          if (layer == 0)
            proj1_kernel<<<dim3(tiles, 1), 256, 0, stream>>>(x, W1 + (size_t)r * IN_F * HID, rs_o, hw,
                                                             (int)n0, (int)n1, (int)chunk);
          else
            proj2_kernel<<<dim3(tiles, 1), 256, 0, stream>>>(acc1, b1, W2 + (size_t)r * HID * HID, rs_o, hw,
                                                             (int)n0, (int)n1, (int)chunk);
          long tot = (long)N_EDGES * HID;
          scatter_kernel<<<(int)((tot + 255) / 256), 256, 0, stream>>>(hw, src + (size_t)r * N_EDGES,
                                                                       dst + (size_t)r * N_EDGES, rs_i,
                                                                       layer == 0 ? acc1 : acc2,
                                                                       1, (int)n0, (int)n1, (int)chunk);
        }
      }
    }
    pool_kernel<<<256, 256, 0, stream>>>(acc2, b2, gid, gpool, gcnt);
    final3_kernel<<<1, 64, 0, stream>>>(gpool, gcnt, Wc, bc, out);
  }
}

// Round 10
// 258.112 us; speedup vs baseline: 1.2781x; 1.2781x over previous
//
#include <hip/hip_runtime.h>

// RGCN vulnerability classifier, fp32 in/out, MI355X.
// r20: r19's block-edge-parallel gather1 REVERTED (measured 129us vs 58us — fewer,
// longer dependent chains with atomic fences cut outstanding requests ~2.4x;
// many short chains win for latency-bound gathers). Back to r18's per-wave-node
// gather1 + ONE incremental fix: 2-deep manual unroll with dual accumulators
// (two independent edata->Ys chains in flight per slot-stream, same traffic,
// same 25K-block TLP). Everything else byte-identical to r18 (258.7us).

#define N_NODES 100000
#define N_REL   8
#define N_EDGES 80000
#define IN_F    128
#define HID     32
#define N_GRAPHS 64
#define NCAT    (N_REL * HID)       // 256
#define N_KEYS  (N_NODES * N_REL)   // 800000
#define TOT_E   (N_REL * N_EDGES)   // 640000
#define DEG_BLOCKS  (TOT_E / 256)   // 2500
#define GEMM_BLOCKS ((N_NODES / 16 + 3) / 4)   // 1563
#define GID_BLOCKS  ((N_NODES + 1023) / 1024)  // 98

constexpr int TILE = 256;   // tier-3 projection block
constexpr int KC   = 32;

typedef __attribute__((ext_vector_type(8))) short bf16x8;
typedef __attribute__((ext_vector_type(4))) float f32x4;

__device__ __forceinline__ ushort f2bf(float v) {
  unsigned u = __builtin_bit_cast(unsigned, v);
  u = (u + 0x7fffu + ((u >> 16) & 1u)) >> 16;   // RNE
  return (ushort)u;
}
__device__ __forceinline__ float bf2f(ushort h) {
  unsigned u = ((unsigned)h) << 16;
  return __builtin_bit_cast(float, u);
}

__global__ __launch_bounds__(256) void rsqrt_kernel(float* __restrict__ p, int count) {
  int i = blockIdx.x * 256 + threadIdx.x;
  if (i < count) {
    int d = ((const int*)p)[i];
    p[i] = rsqrtf((float)(d < 1 ? 1 : d));
  }
}

// Wt1[n][k] = bf16(W1[r][k][j]), n=r*32+j (B^T for MFMA).
// Vt[n][k] = bf16( sum_j W2[r][k][j]*Wc[j][c] ), n=r*2+c (W2@Wc fold).
__global__ __launch_bounds__(256) void prep_w_kernel(const float* __restrict__ W1, const float* __restrict__ W2,
                                                     const float* __restrict__ Wc,
                                                     ushort* __restrict__ Wt1, ushort* __restrict__ Vt) {
  int i = blockIdx.x * 256 + threadIdx.x;
  if (i < NCAT * IN_F) {
    int n = i >> 7, k = i & 127;
    int r = n >> 5, j = n & 31;
    Wt1[i] = f2bf(W1[r * (IN_F * HID) + k * HID + j]);
  } else {
    int q = i - NCAT * IN_F;
    if (q < 16 * HID) {
      int n = q >> 5, k = q & 31;
      int r = n >> 1, c = n & 1;
      float s = 0.f;
#pragma unroll
      for (int j = 0; j < HID; j++) s += W2[r * (HID * HID) + k * HID + j] * Wc[j * 2 + c];
      Vt[q] = f2bf(s);
    }
  }
}

// FUSED: deg/cnt histogram (atomic-RMW-bound, ~0 CU use) + gemm1 (MFMA-bound)
// + gid node-count histogram (98 tail blocks, rides in the atomic slack).
__global__ __launch_bounds__(256, 4) void fused_deg_gemm1(const int* __restrict__ src, const int* __restrict__ dst,
                                                          int* __restrict__ dego, int* __restrict__ cnt,
                                                          int* __restrict__ epos,
                                                          const float* __restrict__ A, const ushort* __restrict__ Bt,
                                                          ushort* __restrict__ Y, int M,
                                                          const int* __restrict__ gid, float* __restrict__ gcnt) {
  __shared__ ushort smem[17408];   // gemm path; reused as int hist by gid path
  int bid = blockIdx.x;
  int role, rid;   // 0=gemm 1=deg 2=gid
  if (bid < 2 * GEMM_BLOCKS) { role = bid & 1; rid = bid >> 1; }
  else if (bid < GEMM_BLOCKS + DEG_BLOCKS) { role = 1; rid = GEMM_BLOCKS + (bid - 2 * GEMM_BLOCKS); }
  else { role = 2; rid = bid - (GEMM_BLOCKS + DEG_BLOCKS); }

  if (role == 1) {
    // ---- deg role: one edge per thread ----
    int i = rid * 256 + (int)threadIdx.x;
    int s = src[i], d = dst[i];
    int r = i / N_EDGES;
    atomicAdd(&dego[r * N_NODES + s], 1);
    epos[i] = atomicAdd(&cnt[d * N_REL + r], 1);
    return;
  }
  if (role == 2) {
    // ---- gid node-count histogram ----
    int* gh = (int*)smem;
    int t = threadIdx.x;
    if (t < N_GRAPHS) gh[t] = 0;
    __syncthreads();
    int base = rid * 1024;
#pragma unroll
    for (int k = 0; k < 4; k++) {
      int n = base + k * 256 + t;
      if (n < N_NODES) atomicAdd(&gh[gid[n]], 1);
    }
    __syncthreads();
    if (t < N_GRAPHS) atomicAdd(&gcnt[t], (float)gh[t]);
    return;
  }

  // ---- gemm role ----
  int wave = __builtin_amdgcn_readfirstlane(threadIdx.x >> 6);
  int lane = threadIdx.x & 63;
  int t = threadIdx.x;
  int m0 = (rid * 4 + wave) * 16;
  int me = (m0 <= M - 16) ? m0 : (M - 16);   // clamped row base for all loads
  int row = lane & 15, quad = lane >> 4;

  bf16x8 af[4];
#pragma unroll
  for (int kq = 0; kq < 4; kq++) {
    const float* ap = &A[(size_t)(me + row) * IN_F + kq * 32 + quad * 8];
    float4 a0 = *(const float4*)ap;
    float4 a1 = *(const float4*)(ap + 4);
    bf16x8 a;
    a[0] = (short)f2bf(a0.x); a[1] = (short)f2bf(a0.y); a[2] = (short)f2bf(a0.z); a[3] = (short)f2bf(a0.w);
    a[4] = (short)f2bf(a1.x); a[5] = (short)f2bf(a1.y); a[6] = (short)f2bf(a1.z); a[7] = (short)f2bf(a1.w);
    af[kq] = a;
  }

  f32x4 acc[16];
#pragma unroll
  for (int nt = 0; nt < 16; nt++) acc[nt] = (f32x4){0.f, 0.f, 0.f, 0.f};

  for (int p = 0; p < 2; p++) {
    __syncthreads();
    const ushort* bsrc = Bt + (size_t)p * (128 * IN_F);
#pragma unroll
    for (int i = 0; i < 8; i++) {
      int c = t + i * 256;
      int rr2 = c >> 4, cc = c & 15;
      uint4 v = *(const uint4*)&bsrc[rr2 * IN_F + cc * 8];
      *(uint4*)&smem[rr2 * 136 + cc * 8] = v;
    }
    __syncthreads();
#pragma unroll
    for (int kq = 0; kq < 4; kq++) {
#pragma unroll
      for (int nt2 = 0; nt2 < 8; nt2++) {
        bf16x8 b = *(const bf16x8*)&smem[(nt2 * 16 + row) * 136 + kq * 32 + quad * 8];
        acc[p * 8 + nt2] = __builtin_amdgcn_mfma_f32_16x16x32_bf16(af[kq], b, acc[p * 8 + nt2], 0, 0, 0);
      }
    }
  }
  __syncthreads();

  ushort* myt = &smem[wave * 4160];
#pragma unroll
  for (int nt = 0; nt < 16; nt++) {
#pragma unroll
    for (int i = 0; i < 4; i++)
      myt[(quad * 4 + i) * 260 + nt * 16 + row] = f2bf(acc[nt][i]);
  }
  if (m0 <= M - 16) {
    ushort* ybase = &Y[(size_t)m0 * NCAT];
#pragma unroll
    for (int k = 0; k < 8; k++) {
      int g = k * 512 + lane * 8;
      int r2 = g >> 8, c2 = g & 255;
      const ushort* sp = &myt[r2 * 260 + c2];
      uint4 v;
      v.x = *(const uint*)(sp + 0);
      v.y = *(const uint*)(sp + 2);
      v.z = *(const uint*)(sp + 4);
      v.w = *(const uint*)(sp + 6);
      *(uint4*)&ybase[g] = v;
    }
  }
}

// ---- exclusive scan over cnt[N_KEYS] -> rp (block-local; part adds by consumers) ----
__global__ __launch_bounds__(256) void scan1_kernel(const int* __restrict__ in, int* __restrict__ out,
                                                    int* __restrict__ partial, int n) {
  __shared__ int ts[256];
  int b0 = blockIdx.x * 1024;
  int t = threadIdx.x;
  int v[4]; int s = 0;
#pragma unroll
  for (int k = 0; k < 4; k++) {
    int idx = b0 + t * 4 + k;
    v[k] = s;
    s += (idx < n) ? in[idx] : 0;
  }
  ts[t] = s;
  __syncthreads();
  for (int off = 1; off < 256; off <<= 1) {
    int xv = (t >= off) ? ts[t - off] : 0;
    __syncthreads();
    ts[t] += xv;
    __syncthreads();
  }
  int texcl = (t == 0) ? 0 : ts[t - 1];
#pragma unroll
  for (int k = 0; k < 4; k++) {
    int idx = b0 + t * 4 + k;
    if (idx < n) out[idx] = texcl + v[k];
  }
  if (t == 255) {
    partial[blockIdx.x] = ts[255];
    if (b0 + 1024 >= n) out[n] = ts[255];   // unique last covering block
  }
}

__global__ __launch_bounds__(256) void scan2_kernel(int* __restrict__ partial, int nb) {
  __shared__ int ts[256];
  int t = threadIdx.x;
  int v[4]; int s = 0;
#pragma unroll
  for (int k = 0; k < 4; k++) {
    int idx = t * 4 + k;
    v[k] = s;
    s += (idx < nb) ? partial[idx] : 0;
  }
  ts[t] = s;
  __syncthreads();
  for (int off = 1; off < 256; off <<= 1) {
    int xv = (t >= off) ? ts[t - off] : 0;
    __syncthreads();
    ts[t] += xv;
    __syncthreads();
  }
  int texcl = (t == 0) ? 0 : ts[t - 1];
#pragma unroll
  for (int k = 0; k < 4; k++) {
    int idx = t * 4 + k;
    if (idx < nb) partial[idx] = texcl + v[k];
  }
}

// CSR fill, atomic-free: slot = rp(key)+epos[i]. 16B record {ecol1, w, d, 0}.
__global__ __launch_bounds__(256) void fill_kernel(const int* __restrict__ src, const int* __restrict__ dst,
                                                   const int* __restrict__ rp, const int* __restrict__ part,
                                                   const int* __restrict__ epos, const int* __restrict__ dego,
                                                   int4* __restrict__ edata) {
  int i = blockIdx.x * 256 + threadIdx.x;
  int d = dst[i];
  int s = src[i];
  int r = i / N_EDGES;
  int key = d * N_REL + r;
  int b = rp[key] + part[key >> 10];
  int k1 = key + 1;
  int e2 = rp[k1] + part[k1 >> 10];
  int c = e2 - b;
  int t = b + epos[i];
  int dg = dego[r * N_NODES + s];
  float w = rsqrtf((float)(dg < 1 ? 1 : dg)) * rsqrtf((float)(c < 1 ? 1 : c));
  int4 e;
  e.x = s * NCAT + r * HID;            // ushort index into Ys (ecol2 = e.x>>4)
  e.y = __builtin_bit_cast(int, w);
  e.z = d;
  e.w = 0;
  edata[t] = e;
}

// Gather layer1 FUSED with layer-2 projection: one wave per dst node (25K blocks,
// max TLP). lane&31 = feature, lane>>5 = 2-way slot streams; each stream runs a
// 2-deep unrolled dual-accumulator loop (two independent edata->Ys chains in
// flight). Then shfl fold + bias/relu + 32-shfl matvec (r18-proven tail).
__global__ __launch_bounds__(256) void gather1_kernel(const ushort* __restrict__ Ys, const int4* __restrict__ edata,
                                                      const int* __restrict__ rp, const int* __restrict__ part,
                                                      const float* __restrict__ b1, const ushort* __restrict__ Vt,
                                                      float* __restrict__ Ys2) {
  int wave = __builtin_amdgcn_readfirstlane(threadIdx.x >> 6);
  int lane = threadIdx.x & 63;
  int d = blockIdx.x * 4 + wave;
  if (d >= N_NODES) return;
  int j = lane & 31, half = lane >> 5;
  int k0 = d * N_REL, k1 = k0 + N_REL;
  int base = rp[k0] + part[k0 >> 10];
  int endp = rp[k1] + part[k1 >> 10];
  float sum0 = 0.f, sum1 = 0.f;
  int t = base + half;
  for (; t + 2 < endp; t += 4) {           // 2 chains in flight
    int4 e0 = edata[t];
    int4 e1 = edata[t + 2];
    float a0 = bf2f(Ys[(size_t)e0.x + j]);
    float a1 = bf2f(Ys[(size_t)e1.x + j]);
    sum0 += __builtin_bit_cast(float, e0.y) * a0;
    sum1 += __builtin_bit_cast(float, e1.y) * a1;
  }
  if (t < endp) {
    int4 e = edata[t];
    sum0 += __builtin_bit_cast(float, e.y) * bf2f(Ys[(size_t)e.x + j]);
  }
  float sum = sum0 + sum1;
  sum += __shfl_down(sum, 32);
  float sb = 0.f;
#pragma unroll
  for (int q = 0; q < N_REL; q++) sb += b1[q * HID + j];
  float h = fmaxf(sum + sb, 0.f);          // valid on lanes 0..31
  bf16x8 vrow[4];
  if (lane < 16) {
#pragma unroll
    for (int q = 0; q < 4; q++) vrow[q] = *(const bf16x8*)&Vt[lane * HID + q * 8];
  } else {
#pragma unroll
    for (int q = 0; q < 4; q++) vrow[q] = (bf16x8){0,0,0,0,0,0,0,0};
  }
  float acc = 0.f;
#pragma unroll
  for (int jj = 0; jj < 32; jj++) {
    float hv = __shfl(h, jj);
    acc += hv * bf2f((ushort)vrow[jj >> 3][jj & 7]);
  }
  if (lane < 16) Ys2[(size_t)d * 16 + lane] = acc;
}

// Gather layer2 + pooling, STREAMING: grid-stride over slots; gid[e.z] is
// d-ordered (quasi-sequential); only Ys2 read is random. Counts via gid hist.
__global__ __launch_bounds__(256) void gather2_pool_kernel(const float* __restrict__ Ys2,
                                                           const int4* __restrict__ edata,
                                                           const int* __restrict__ gid,
                                                           float* __restrict__ gpool) {
  __shared__ float lp[N_GRAPHS * 2];
  int t = threadIdx.x;
  if (t < N_GRAPHS * 2) lp[t] = 0.f;
  __syncthreads();
  for (int sidx = blockIdx.x * 256 + t; sidx < TOT_E; sidx += gridDim.x * 256) {
    int4 e = edata[sidx];
    float w = __builtin_bit_cast(float, e.y);
    float2 y = *(const float2*)&Ys2[e.x >> 4];
    int g = gid[e.z];
    atomicAdd(&lp[g * 2 + 0], w * y.x);
    atomicAdd(&lp[g * 2 + 1], w * y.y);
  }
  __syncthreads();
  if (t < N_GRAPHS * 2) atomicAdd(&gpool[t], lp[t]);
}

// out[g] = gpool[g]/cnt + (sum_r b2[r]) @ Wc + bc   (cnt==0 -> bc exactly)
__global__ void final_kernel(const float* __restrict__ gpool, const float* __restrict__ gcnt,
                             const float* __restrict__ b2, const float* __restrict__ Wc,
                             const float* __restrict__ bc, float* __restrict__ out) {
  int g = threadIdx.x;
  if (g >= N_GRAPHS) return;
  float c0 = 0.f, c1 = 0.f;
#pragma unroll
  for (int k = 0; k < HID; k++) {
    float sb = 0.f;
#pragma unroll
    for (int r = 0; r < N_REL; r++) sb += b2[r * HID + k];
    c0 += sb * Wc[k * 2 + 0];
    c1 += sb * Wc[k * 2 + 1];
  }
  float cntv = gcnt[g];
  if (cntv > 0.f) {
    out[g * 2 + 0] = gpool[g * 2 + 0] / cntv + c0 + bc[0];
    out[g * 2 + 1] = gpool[g * 2 + 1] / cntv + c1 + bc[1];
  } else {
    out[g * 2 + 0] = bc[0];
    out[g * 2 + 1] = bc[1];
  }
}

// ---- Tier-3 fp32 fallback kernels (small ws) ----
__global__ __launch_bounds__(256) void deg_kernel(const int* __restrict__ src, const int* __restrict__ dst,
                                                  int* __restrict__ dego, int* __restrict__ degi, int n_rel) {
  int i = blockIdx.x * 256 + threadIdx.x;
  if (i < n_rel * N_EDGES) {
    int r = i / N_EDGES;
    atomicAdd(&dego[r * N_NODES + src[i]], 1);
    atomicAdd(&degi[r * N_NODES + dst[i]], 1);
  }
}

__global__ __launch_bounds__(256) void proj1_kernel(const float* __restrict__ x, const float* __restrict__ W1r0,
                                                    const float* __restrict__ rs_o, float* __restrict__ hw,
                                                    int n0, int n1, int hw_nodes) {
  int rr = blockIdx.y;
  int nb = n0 + blockIdx.x * TILE;
  int t = threadIdx.x;
  __shared__ float xs[TILE][KC + 4];
  const float* __restrict__ Wr = W1r0 + (size_t)rr * (IN_F * HID);
  float acc[HID];
#pragma unroll
  for (int j = 0; j < HID; j++) acc[j] = 0.f;
  for (int kc = 0; kc < IN_F; kc += KC) {
    __syncthreads();
#pragma unroll
    for (int i = 0; i < (TILE * KC / 4) / 256; i++) {
      int q = t + i * 256;
      int nn = q >> 3, k4 = q & 7;
      int n = nb + nn;
      float4 v = make_float4(0.f, 0.f, 0.f, 0.f);
      if (n < n1) v = *(const float4*)&x[(size_t)n * IN_F + kc + k4 * 4];
      *(float4*)&xs[nn][k4 * 4] = v;
    }
    __syncthreads();
#pragma unroll
    for (int k4 = 0; k4 < KC / 4; k4++) {
      float4 xv = *(const float4*)&xs[t][k4 * 4];
      const float* wk = &Wr[(kc + k4 * 4) * HID];
#pragma unroll
      for (int j = 0; j < HID; j++) acc[j] += xv.x * wk[j];
#pragma unroll
      for (int j = 0; j < HID; j++) acc[j] += xv.y * wk[HID + j];
#pragma unroll
      for (int j = 0; j < HID; j++) acc[j] += xv.z * wk[2 * HID + j];
#pragma unroll
      for (int j = 0; j < HID; j++) acc[j] += xv.w * wk[3 * HID + j];
    }
  }
  int n = nb + t;
  if (n < n1) {
    float s = rs_o[(size_t)rr * N_NODES + n];
    float* o = &hw[((size_t)rr * hw_nodes + (n - n0)) * HID];
#pragma unroll
    for (int j4 = 0; j4 < HID / 4; j4++) {
      float4 v = make_float4(acc[j4 * 4] * s, acc[j4 * 4 + 1] * s, acc[j4 * 4 + 2] * s, acc[j4 * 4 + 3] * s);
      *(float4*)&o[j4 * 4] = v;
    }
  }
}

__global__ __launch_bounds__(256) void proj2_kernel(const float* __restrict__ acc1, const float* __restrict__ b1,
                                                    const float* __restrict__ W2r0, const float* __restrict__ rs_o,
                                                    float* __restrict__ hw, int n0, int n1, int hw_nodes) {
  int n = n0 + blockIdx.x * 256 + threadIdx.x;
  if (n >= n1) return;
  int rr = blockIdx.y;
  float h1[HID];
#pragma unroll
  for (int j4 = 0; j4 < HID / 4; j4++) {
    float4 v = *(const float4*)&acc1[(size_t)n * HID + j4 * 4];
    h1[j4 * 4 + 0] = v.x; h1[j4 * 4 + 1] = v.y; h1[j4 * 4 + 2] = v.z; h1[j4 * 4 + 3] = v.w;
  }
#pragma unroll
  for (int j = 0; j < HID; j++) {
    float sb = 0.f;
#pragma unroll
    for (int q = 0; q < N_REL; q++) sb += b1[q * HID + j];
    h1[j] = fmaxf(h1[j] + sb, 0.f);
  }
  const float* __restrict__ Wr = W2r0 + (size_t)rr * (HID * HID);
  float acc[HID];
#pragma unroll
  for (int j = 0; j < HID; j++) acc[j] = 0.f;
#pragma unroll
  for (int k = 0; k < HID; k++) {
    float hv = h1[k];
#pragma unroll
    for (int j = 0; j < HID; j++) acc[j] += hv * Wr[k * HID + j];
  }
  float s = rs_o[(size_t)rr * N_NODES + n];
  float* o = &hw[((size_t)rr * hw_nodes + (n - n0)) * HID];
#pragma unroll
  for (int j4 = 0; j4 < HID / 4; j4++) {
    float4 v = make_float4(acc[j4 * 4] * s, acc[j4 * 4 + 1] * s, acc[j4 * 4 + 2] * s, acc[j4 * 4 + 3] * s);
    *(float4*)&o[j4 * 4] = v;
  }
}

__global__ __launch_bounds__(256) void scatter_kernel(const float* __restrict__ hw, const int* __restrict__ src,
                                                      const int* __restrict__ dst, const float* __restrict__ rs_i,
                                                      float* __restrict__ acc, int nr, int n0, int n1, int hw_nodes) {
  long i = (long)blockIdx.x * 256 + threadIdx.x;
  long total = (long)nr * N_EDGES * HID;
  if (i >= total) return;
  int j = (int)(i & (HID - 1));
  long e = i >> 5;
  int rr = (int)(e / N_EDGES);
  int ee = (int)(e - (long)rr * N_EDGES);
  int s = src[rr * N_EDGES + ee];
  if (s < n0 || s >= n1) return;
  int d = dst[rr * N_EDGES + ee];
  float v = hw[((size_t)rr * hw_nodes + (s - n0)) * HID + j] * rs_i[(size_t)rr * N_NODES + d];
  atomicAdd(&acc[(size_t)d * HID + j], v);
}

__global__ __launch_bounds__(256) void pool_kernel(const float* __restrict__ acc2, const float* __restrict__ b2,
                                                   const int* __restrict__ gid, float* __restrict__ gpool,
                                                   float* __restrict__ gcnt) {
  __shared__ float lp[N_GRAPHS * HID];
  __shared__ float lc[N_GRAPHS];
  int t = threadIdx.x;
  for (int i = t; i < N_GRAPHS * HID; i += 256) lp[i] = 0.f;
  if (t < N_GRAPHS) lc[t] = 0.f;
  __syncthreads();
  int j = t & (HID - 1);
  int grp = t >> 5;
  float sb = 0.f;
#pragma unroll
  for (int q = 0; q < N_REL; q++) sb += b2[q * HID + j];
  for (int n = blockIdx.x * 8 + grp; n < N_NODES; n += gridDim.x * 8) {
    int g = gid[n];
    float v = acc2[(size_t)n * HID + j] + sb;
    atomicAdd(&lp[g * HID + j], v);
    if (j == 0) atomicAdd(&lc[g], 1.f);
  }
  __syncthreads();
  for (int i = t; i < N_GRAPHS * HID; i += 256) atomicAdd(&gpool[i], lp[i]);
  if (t < N_GRAPHS) atomicAdd(&gcnt[t], lc[t]);
}

__global__ void final3_kernel(const float* __restrict__ gpool, const float* __restrict__ gcnt,
                              const float* __restrict__ Wc, const float* __restrict__ bc,
                              float* __restrict__ out) {
  int g = threadIdx.x;
  if (g >= N_GRAPHS) return;
  float inv = 1.f / fmaxf(gcnt[g], 1.f);
  float o0 = bc[0], o1 = bc[1];
#pragma unroll
  for (int k = 0; k < HID; k++) {
    float p = gpool[g * HID + k] * inv;
    o0 += p * Wc[k * 2 + 0];
    o1 += p * Wc[k * 2 + 1];
  }
  out[g * 2 + 0] = o0;
  out[g * 2 + 1] = o1;
}

extern "C" void kernel_launch(void* const* d_in, const int* in_sizes, int n_in,
                              void* d_out, int out_size, void* d_ws, size_t ws_size,
                              hipStream_t stream) {
  const float* x  = (const float*)d_in[0];
  const int* src  = (const int*)d_in[1];
  const int* dst  = (const int*)d_in[2];
  const int* gid  = (const int*)d_in[3];
  const float* W1 = (const float*)d_in[5];
  const float* b1 = (const float*)d_in[6];
  const float* W2 = (const float*)d_in[7];
  const float* b2 = (const float*)d_in[8];
  const float* Wc = (const float*)d_in[9];
  const float* bc = (const float*)d_in[10];
  float* out = (float*)d_out;

  float* ws = (float*)d_ws;
  const size_t NF = (size_t)N_NODES * HID;           // 3.2M
  const size_t RN = (size_t)N_REL * N_NODES;         // 800k
  const size_t POOLF = N_GRAPHS * HID + N_GRAPHS;
  size_t wsf = ws_size / 4;

  const size_t T1_NEED = 22500000;   // ~90 MB (actual ~21.6M float slots)

  if (wsf >= T1_NEED) {
    // ---- Tier 1 layout ----
    float* gpool = ws;                               // 128  (zero region start)
    float* gcnt  = gpool + N_GRAPHS * 2;             // 64
    int*   dego  = (int*)(gcnt + N_GRAPHS);          // RN raw out-degree counts
    int*   cnt   = dego + RN;                        // N_KEYS (raw in-degree counts; zero region end)
    int*   epos  = cnt + N_KEYS;                     // TOT_E (within-bucket ranks)
    int*   rp    = epos + TOT_E;                     // N_KEYS + 8 (block-local scan)
    int*   part  = rp + N_KEYS + 8;                  // 1024
    int4*  edata = (int4*)(part + 1024);             // TOT_E x 16B packed edge records
    float* Ys2   = (float*)(edata + TOT_E);          // N*16
    ushort* Ys   = (ushort*)(Ys2 + (size_t)N_NODES * 16);   // N*256 ushorts
    ushort* Wt1  = Ys + (size_t)N_NODES * NCAT;             // 256*128 ushorts
    ushort* Vt   = Wt1 + NCAT * IN_F;                       // 16*32 ushorts

    size_t zbytes = (N_GRAPHS * 3 + RN + (size_t)N_KEYS) * 4;   // ~6.4 MB
    hipMemsetAsync(ws, 0, zbytes, stream);

    prep_w_kernel<<<(NCAT * IN_F + 16 * HID + 255) / 256, 256, 0, stream>>>(W1, W2, Wc, Wt1, Vt);
    fused_deg_gemm1<<<DEG_BLOCKS + GEMM_BLOCKS + GID_BLOCKS, 256, 0, stream>>>(src, dst, dego, cnt, epos,
                                                                               x, Wt1, Ys, N_NODES, gid, gcnt);

    int sblocks = (N_KEYS + 1023) / 1024;
    scan1_kernel<<<sblocks, 256, 0, stream>>>(cnt, rp, part, N_KEYS);
    scan2_kernel<<<1, 256, 0, stream>>>(part, sblocks);
    fill_kernel<<<TOT_E / 256, 256, 0, stream>>>(src, dst, rp, part, epos, dego, edata);

    int nblocks = (N_NODES + 3) / 4;
    gather1_kernel<<<nblocks, 256, 0, stream>>>(Ys, edata, rp, part, b1, Vt, Ys2);
    gather2_pool_kernel<<<416, 256, 0, stream>>>(Ys2, edata, gid, gpool);
    final_kernel<<<1, 64, 0, stream>>>(gpool, gcnt, b2, Wc, bc, out);
  } else {
    // ---- Tier 3: fp32 per-relation fallback, node-chunked hw ----
    float* acc1  = ws;
    float* acc2  = acc1 + NF;
    float* gpool = acc2 + NF;
    float* gcnt  = gpool + N_GRAPHS * HID;
    float* rsb   = ws + (2 * NF + POOLF);
    size_t zf = 2 * NF + POOLF;
    float* rs_o = rsb;
    float* rs_i = rsb + N_NODES;
    float* hw = rsb + 2 * N_NODES;
    size_t fixed3 = zf + 2 * N_NODES;
    size_t avail = (wsf > fixed3) ? (wsf - fixed3) : 0;
    long chunk = (long)(avail / HID) & ~255L;
    if (chunk < 256) chunk = 256;
    if (chunk > N_NODES) chunk = N_NODES;

    size_t zb = zf * 4; if (zb > ws_size) zb = ws_size;
    hipMemsetAsync(d_ws, 0, zb, stream);

    for (int layer = 0; layer < 2; layer++) {
      for (int r = 0; r < N_REL; r++) {
        hipMemsetAsync(rs_o, 0, 2 * N_NODES * 4, stream);
        deg_kernel<<<(N_EDGES + 255) / 256, 256, 0, stream>>>(src + (size_t)r * N_EDGES, dst + (size_t)r * N_EDGES,
                                                              (int*)rs_o, (int*)rs_i, 1);
        rsqrt_kernel<<<(2 * N_NODES + 255) / 256, 256, 0, stream>>>(rs_o, 2 * N_NODES);
        for (long n0 = 0; n0 < N_NODES; n0 += chunk) {
          long n1 = n0 + chunk; if (n1 > N_NODES) n1 = N_NODES;
          int tiles = (int)((n1 - n0 + TILE - 1) / TILE);
          if (layer == 0)
            proj1_kernel<<<dim3(tiles, 1), 256, 0, stream>>>(x, W1 + (size_t)r * IN_F * HID, rs_o, hw,
                                                             (int)n0, (int)n1, (int)chunk);
          else
            proj2_kernel<<<dim3(tiles, 1), 256, 0, stream>>>(acc1, b1, W2 + (size_t)r * HID * HID, rs_o, hw,
                                                             (int)n0, (int)n1, (int)chunk);
          long tot = (long)N_EDGES * HID;
          scatter_kernel<<<(int)((tot + 255) / 256), 256, 0, stream>>>(hw, src + (size_t)r * N_EDGES,
                                                                       dst + (size_t)r * N_EDGES, rs_i,
                                                                       layer == 0 ? acc1 : acc2,
                                                                       1, (int)n0, (int)n1, (int)chunk);
        }
      }
    }
    pool_kernel<<<256, 256, 0, stream>>>(acc2, b2, gid, gpool, gcnt);
    final3_kernel<<<1, 64, 0, stream>>>(gpool, gcnt, Wc, bc, out);
  }
}